// Round 1
// 565.565 us; speedup vs baseline: 1.0049x; 1.0049x over previous
//
#include <hip/hip_runtime.h>

#define B_  2
#define NQ  2048
#define NK  2048
#define C_  256
#define H_  8
#define HD  32
#define KT   (NK / 32)             // 64 tiles of 32 keys
#define CH   4                     // tiles per fetch chunk
#define NC   (KT / CH)             // 16 chunks
#define CCOLS (CH * 32)            // 128 keys per chunk
#define QT_  (NQ / 16)             // 128 q-tiles

typedef float f32x4 __attribute__((ext_vector_type(4)));
typedef __bf16 bf16x8 __attribute__((ext_vector_type(8)));
typedef unsigned short ushort8 __attribute__((ext_vector_type(8)));

// f32 -> bf16 round-to-nearest-even
static __device__ __forceinline__ unsigned short f2bf(float f) {
    unsigned int u = __builtin_bit_cast(unsigned int, f);
    u += 0x7FFFu + ((u >> 16) & 1u);
    return (unsigned short)(u >> 16);
}
static __device__ __forceinline__ float bf2f(unsigned short h) {
    unsigned int u = ((unsigned int)h) << 16;
    return __builtin_bit_cast(float, u);
}
// split f32 -> (hi bf16 in low 16, lo bf16 in high 16); hi+lo ~ f to 2^-19 rel
static __device__ __forceinline__ unsigned int split1(float f) {
    unsigned short h = f2bf(f);
    unsigned short l = f2bf(f - bf2f(h));
    return (unsigned int)h | ((unsigned int)l << 16);
}
static __device__ __forceinline__ bf16x8 ld_bf16x8(const unsigned short* p) {
    return __builtin_bit_cast(bf16x8, *(const ushort8*)p);
}
// async global->LDS, 16B per lane; LDS dest = wave-uniform base + lane*16
static __device__ __forceinline__ void async16(const void* g, void* l) {
    __builtin_amdgcn_global_load_lds((__attribute__((address_space(1))) void*)g,
                                     (__attribute__((address_space(3))) void*)l,
                                     16, 0, 0);
}

// ---------------------------------------------------------------------------
// Pack mask (int32 [NQ][NK]) into per-qtile bitmasks: maskb[qt][k] bit q = mask.
// Cuts 33 MB of attn mask reads to ~1 MB and frees attn LDS.
// ---------------------------------------------------------------------------
__global__ __launch_bounds__(256) void maskpack_kernel(const int* __restrict__ mask,
                                                       unsigned short* __restrict__ mb)
{
    const int qt = blockIdx.x;
    const int k  = blockIdx.y * 256 + threadIdx.x;
    unsigned int m = 0;
    #pragma unroll
    for (int r = 0; r < 16; ++r)
        m |= (mask[(size_t)(qt * 16 + r) * NK + k] ? 1u : 0u) << r;
    mb[(size_t)qt * NK + k] = (unsigned short)m;
}

// ---------------------------------------------------------------------------
// Fused Q/K/V projection GEMM (split-bf16 4-term MFMA), selected by blockIdx.z.
// z=0: Q (row layout)  z=1: K (row layout)  z=2: V (transposed layout)
// grid (64,4,3), block 256 (4 waves); tile 64x64, K-step 32.
// W-tile rows padded 32->40 shorts: ds_read_b128 bank conflict 8-way -> ~2-way.
// ---------------------------------------------------------------------------
__global__ __launch_bounds__(256) void proj_kernel(
        const float* __restrict__ query, const float* __restrict__ key,
        const float* __restrict__ value,
        const float* __restrict__ Wq, const float* __restrict__ Wk,
        const float* __restrict__ Wv,
        unsigned short* __restrict__ qbh, unsigned short* __restrict__ qbl,
        unsigned short* __restrict__ kbh, unsigned short* __restrict__ kbl,
        unsigned short* __restrict__ vbh, unsigned short* __restrict__ vbl)
{
    __shared__ unsigned short WtH[64][40];
    __shared__ unsigned short WtL[64][40];

    const int z = blockIdx.z;
    const float* X = (z == 0) ? query : (z == 1) ? key : value;
    const float* W = (z == 0) ? Wq    : (z == 1) ? Wk  : Wv;
    unsigned short* dh = (z == 0) ? qbh : (z == 1) ? kbh : vbh;
    unsigned short* dl = (z == 0) ? qbl : (z == 1) ? kbl : vbl;
    const int vmode = (z == 2);

    const int tid  = threadIdx.x;
    const int wave = tid >> 6;
    const int lane = tid & 63;
    const int n15  = lane & 15;
    const int quad = lane >> 4;
    const int m0   = blockIdx.x * 64;
    const int j0   = blockIdx.y * 64;

    f32x4 acc[4];
    acc[0] = 0.f; acc[1] = 0.f; acc[2] = 0.f; acc[3] = 0.f;

    const int sj  = tid >> 2;
    const int skc = (tid & 3) * 8;
    const float* __restrict__ xrow = X + (size_t)(m0 + wave * 16 + n15) * C_;

    for (int k0 = 0; k0 < C_; k0 += 32) {
        ushort8 wh, wl;
        #pragma unroll
        for (int i = 0; i < 8; ++i) {
            unsigned int p = split1(W[(size_t)(k0 + skc + i) * C_ + j0 + sj]);
            wh[i] = (unsigned short)p;
            wl[i] = (unsigned short)(p >> 16);
        }
        *(ushort8*)&WtH[sj][skc] = wh;
        *(ushort8*)&WtL[sj][skc] = wl;
        __syncthreads();

        f32x4 a0 = *(const f32x4*)(xrow + k0 + quad * 8);
        f32x4 a1 = *(const f32x4*)(xrow + k0 + quad * 8 + 4);
        ushort8 ah, al;
        #pragma unroll
        for (int i = 0; i < 4; ++i) {
            unsigned int p0 = split1(a0[i]);
            unsigned int p1 = split1(a1[i]);
            ah[i]     = (unsigned short)p0;  al[i]     = (unsigned short)(p0 >> 16);
            ah[i + 4] = (unsigned short)p1;  al[i + 4] = (unsigned short)(p1 >> 16);
        }
        bf16x8 Ah = __builtin_bit_cast(bf16x8, ah);
        bf16x8 Al = __builtin_bit_cast(bf16x8, al);

        #pragma unroll
        for (int f = 0; f < 4; ++f) {
            bf16x8 Bh = ld_bf16x8(&WtH[f * 16 + n15][quad * 8]);
            bf16x8 Bl = ld_bf16x8(&WtL[f * 16 + n15][quad * 8]);
            acc[f] = __builtin_amdgcn_mfma_f32_16x16x32_bf16(Al, Bl, acc[f], 0, 0, 0);
            acc[f] = __builtin_amdgcn_mfma_f32_16x16x32_bf16(Al, Bh, acc[f], 0, 0, 0);
            acc[f] = __builtin_amdgcn_mfma_f32_16x16x32_bf16(Ah, Bl, acc[f], 0, 0, 0);
            acc[f] = __builtin_amdgcn_mfma_f32_16x16x32_bf16(Ah, Bh, acc[f], 0, 0, 0);
        }
        __syncthreads();
    }

    #pragma unroll
    for (int f = 0; f < 4; ++f) {
        const int j = j0 + f * 16 + n15;
        const int h = j >> 5, dd = j & 31;
        #pragma unroll
        for (int r = 0; r < 4; ++r) {
            const int grow = m0 + wave * 16 + quad * 4 + r;
            const int b = grow >> 11, row = grow & 2047;
            unsigned int p = split1(acc[f][r]);
            size_t idx;
            if (vmode) idx = (size_t)((b * H_ + h) * HD + dd) * NK + row;
            else       idx = (size_t)((b * H_ + h) * NK + row) * HD + dd;
            dh[idx] = (unsigned short)p;
            dl[idx] = (unsigned short)(p >> 16);
        }
    }
}

// ---------------------------------------------------------------------------
// Output projection: out[m,j] = sum_k x[m,k]*Wp[k,j] + bp[j], f32 out.
// ---------------------------------------------------------------------------
__global__ __launch_bounds__(256) void outproj_kernel(const unsigned short* __restrict__ Xh,
                                                      const unsigned short* __restrict__ Xl,
                                                      const float* __restrict__ W,
                                                      const float* __restrict__ bias,
                                                      float* __restrict__ out)
{
    __shared__ unsigned short WtH[64][40];
    __shared__ unsigned short WtL[64][40];

    const int tid  = threadIdx.x;
    const int wave = tid >> 6;
    const int lane = tid & 63;
    const int n15  = lane & 15;
    const int quad = lane >> 4;
    const int m0   = blockIdx.x * 64;
    const int j0   = blockIdx.y * 64;

    f32x4 acc[4];
    acc[0] = 0.f; acc[1] = 0.f; acc[2] = 0.f; acc[3] = 0.f;

    const int sj  = tid >> 2;
    const int skc = (tid & 3) * 8;
    const size_t xoff = (size_t)(m0 + wave * 16 + n15) * C_;

    for (int k0 = 0; k0 < C_; k0 += 32) {
        ushort8 wh, wl;
        #pragma unroll
        for (int i = 0; i < 8; ++i) {
            unsigned int p = split1(W[(size_t)(k0 + skc + i) * C_ + j0 + sj]);
            wh[i] = (unsigned short)p;
            wl[i] = (unsigned short)(p >> 16);
        }
        *(ushort8*)&WtH[sj][skc] = wh;
        *(ushort8*)&WtL[sj][skc] = wl;
        __syncthreads();

        bf16x8 Ah = ld_bf16x8(Xh + xoff + k0 + quad * 8);
        bf16x8 Al = ld_bf16x8(Xl + xoff + k0 + quad * 8);

        #pragma unroll
        for (int f = 0; f < 4; ++f) {
            bf16x8 Bh = ld_bf16x8(&WtH[f * 16 + n15][quad * 8]);
            bf16x8 Bl = ld_bf16x8(&WtL[f * 16 + n15][quad * 8]);
            acc[f] = __builtin_amdgcn_mfma_f32_16x16x32_bf16(Al, Bl, acc[f], 0, 0, 0);
            acc[f] = __builtin_amdgcn_mfma_f32_16x16x32_bf16(Al, Bh, acc[f], 0, 0, 0);
            acc[f] = __builtin_amdgcn_mfma_f32_16x16x32_bf16(Ah, Bl, acc[f], 0, 0, 0);
            acc[f] = __builtin_amdgcn_mfma_f32_16x16x32_bf16(Ah, Bh, acc[f], 0, 0, 0);
        }
        __syncthreads();
    }

    #pragma unroll
    for (int f = 0; f < 4; ++f) {
        const int j = j0 + f * 16 + n15;
        const float bj = bias[j];
        #pragma unroll
        for (int r = 0; r < 4; ++r) {
            const int grow = m0 + wave * 16 + quad * 4 + r;
            out[(size_t)grow * C_ + j] = acc[f][r] + bj;
        }
    }
}

// ---------------------------------------------------------------------------
// Flash attention, NO split-K. grid 256 = B * (Nq/16), 1 WG/CU; block 512.
// Wave w == head w. Per 128-key chunk:
//   syncthreads (drains exactly this chunk's sim asyncs)
//   head-sum once per chunk (LDS) + syncthreads (vmcnt==0 here: free)
//   all K/V/mask loads for 4 tiles, THEN sim asyncs for chunk c+1
//     -> compiler's counted vmcnt waits for K/V while keeping the 8 asyncs
//        in flight across the barrier-free 4-tile compute.
// Sim fetch bursts are 16 rows x 512B (vs 128B before): 4x DRAM page payload.
// LDS 149.5 KB -> 1 WG/CU (deliberate: kernel is HBM-bound, not occupancy).
// ---------------------------------------------------------------------------
__global__ __launch_bounds__(512, 2) void attn_kernel(
        const unsigned short* __restrict__ qh, const unsigned short* __restrict__ ql,
        const unsigned short* __restrict__ kh, const unsigned short* __restrict__ kl,
        const unsigned short* __restrict__ vh, const unsigned short* __restrict__ vl,
        const float* __restrict__ sim, const unsigned short* __restrict__ maskb,
        unsigned short* __restrict__ xh, unsigned short* __restrict__ xl)
{
    __shared__ __align__(16) float simC[2][H_][16][CCOLS];      // 128 KB
    __shared__ float hsum[16][CCOLS];                           // 8 KB
    __shared__ __align__(16) unsigned short pLds[H_][16 * 40];  // 10 KB

    const int tid  = threadIdx.x;
    const int wave = tid >> 6;    // head
    const int lane = tid & 63;
    const int n15  = lane & 15;
    const int quad = lane >> 4;

    const int wg = blockIdx.x;
    const int b  = wg >> 7;
    const int qt = wg & 127;
    const int q0 = qt * 16;

    const size_t bh   = (size_t)(b * H_ + wave);
    const size_t qoff = (bh * NQ + q0 + n15) * HD + quad * 8;
    const unsigned short* khb = kh + bh * NK * HD;
    const unsigned short* klb = kl + bh * NK * HD;
    const unsigned short* vhb = vh + bh * HD * NK;
    const unsigned short* vlb = vl + bh * HD * NK;
    const unsigned short* mkb = maskb + (size_t)qt * NK;
    // per-lane async src: row = lane>>5 (2 rows x 512B per 1KB call)
    const float* gsim = sim + (bh * NQ + q0 + (lane >> 5)) * (size_t)NK
                            + (lane & 31) * 4;

    const bf16x8 Qh = ld_bf16x8(qh + qoff);
    const bf16x8 Ql = ld_bf16x8(ql + qoff);

    f32x4 O0 = 0.f, O1 = 0.f;
    float m_r[4] = {0.f, 0.f, 0.f, 0.f};   // m-floor 0 (scores << 88, safe)
    float l_r[4] = {0.f, 0.f, 0.f, 0.f};

    const float scale = 0.17677669529663687f;  // 1/sqrt(32)

    auto fetch_chunk = [&](int c, int buf) {
        const float* g = gsim + (size_t)c * CCOLS;
        #pragma unroll
        for (int ci = 0; ci < 8; ++ci)
            async16(g + (size_t)(2 * ci) * NK, &simC[buf][wave][2 * ci][0]);
    };

    auto headsum_phase = [&](int cur) {
        const int qq = tid >> 5, kk = tid & 31;
        #pragma unroll
        for (int j = 0; j < 4; ++j) {
            float sum = 0.f;
            #pragma unroll
            for (int h = 0; h < H_; ++h) sum += simC[cur][h][qq][kk + 32 * j];
            hsum[qq][kk + 32 * j] = -0.125f * sum;   // = -mean over 8 heads
        }
    };

    struct KVT {
        bf16x8 kh[CH][2], kl[CH][2], vh[CH][2], vl[CH][2];
        unsigned short mb[CH][2];
    };

    auto load_kv = [&](int c, KVT& kv) {
        #pragma unroll
        for (int t = 0; t < CH; ++t) {
            const int k0 = c * CCOLS + t * 32;
            const size_t koA = (size_t)(k0 + n15) * HD + quad * 8;
            const size_t koB = (size_t)(k0 + 16 + n15) * HD + quad * 8;
            kv.kh[t][0] = ld_bf16x8(khb + koA); kv.kl[t][0] = ld_bf16x8(klb + koA);
            kv.kh[t][1] = ld_bf16x8(khb + koB); kv.kl[t][1] = ld_bf16x8(klb + koB);
            const size_t voA = (size_t)n15 * NK + k0 + quad * 8;
            const size_t voB = (size_t)(16 + n15) * NK + k0 + quad * 8;
            kv.vh[t][0] = ld_bf16x8(vhb + voA); kv.vl[t][0] = ld_bf16x8(vlb + voA);
            kv.vh[t][1] = ld_bf16x8(vhb + voB); kv.vl[t][1] = ld_bf16x8(vlb + voB);
            kv.mb[t][0] = mkb[k0 + n15];
            kv.mb[t][1] = mkb[k0 + 16 + n15];
        }
    };

    auto chunk_body = [&](int cur, const KVT& kv) {
        unsigned short* pw = pLds[wave];
        #pragma unroll
        for (int t = 0; t < CH; ++t) {
            const int tc = t * 32;
            f32x4 S0 = 0.f, S1 = 0.f;
            S0 = __builtin_amdgcn_mfma_f32_16x16x32_bf16(Ql, kv.kl[t][0], S0, 0, 0, 0);
            S0 = __builtin_amdgcn_mfma_f32_16x16x32_bf16(Ql, kv.kh[t][0], S0, 0, 0, 0);
            S0 = __builtin_amdgcn_mfma_f32_16x16x32_bf16(Qh, kv.kl[t][0], S0, 0, 0, 0);
            S0 = __builtin_amdgcn_mfma_f32_16x16x32_bf16(Qh, kv.kh[t][0], S0, 0, 0, 0);
            S1 = __builtin_amdgcn_mfma_f32_16x16x32_bf16(Ql, kv.kl[t][1], S1, 0, 0, 0);
            S1 = __builtin_amdgcn_mfma_f32_16x16x32_bf16(Ql, kv.kh[t][1], S1, 0, 0, 0);
            S1 = __builtin_amdgcn_mfma_f32_16x16x32_bf16(Qh, kv.kl[t][1], S1, 0, 0, 0);
            S1 = __builtin_amdgcn_mfma_f32_16x16x32_bf16(Qh, kv.kh[t][1], S1, 0, 0, 0);

            unsigned int u0[4], u1[4];
            #pragma unroll
            for (int r = 0; r < 4; ++r) {
                const int qq = quad * 4 + r;
                float s0 = S0[r] * scale + simC[cur][wave][qq][tc + n15]
                         + hsum[qq][tc + n15];
                float s1 = S1[r] * scale + simC[cur][wave][qq][tc + 16 + n15]
                         + hsum[qq][tc + 16 + n15];
                if (!((kv.mb[t][0] >> qq) & 1)) s0 = -1e30f;
                if (!((kv.mb[t][1] >> qq) & 1)) s1 = -1e30f;

                float mx = fmaxf(s0, s1);
                #pragma unroll
                for (int off = 1; off < 16; off <<= 1) mx = fmaxf(mx, __shfl_xor(mx, off));
                const float mnew = fmaxf(m_r[r], mx);
                const float a  = __expf(m_r[r] - mnew);
                const float p0 = __expf(s0 - mnew);
                const float p1 = __expf(s1 - mnew);
                float sm = p0 + p1;
                #pragma unroll
                for (int off = 1; off < 16; off <<= 1) sm += __shfl_xor(sm, off);
                l_r[r] = l_r[r] * a + sm;
                m_r[r] = mnew;
                O0[r] *= a; O1[r] *= a;
                u0[r] = split1(p0); u1[r] = split1(p1);
            }

            // P (C-layout) -> per-wave LDS -> A-frag; two passes (hi, then lo)
            // through one bf16 buffer (per-wave DS ops are in-order).
            #pragma unroll
            for (int r = 0; r < 4; ++r) {
                const int qq = quad * 4 + r;
                pw[qq * 40 + n15]      = (unsigned short)u0[r];
                pw[qq * 40 + 16 + n15] = (unsigned short)u1[r];
            }
            bf16x8 Ph = ld_bf16x8(pw + n15 * 40 + quad * 8);
            #pragma unroll
            for (int r = 0; r < 4; ++r) {
                const int qq = quad * 4 + r;
                pw[qq * 40 + n15]      = (unsigned short)(u0[r] >> 16);
                pw[qq * 40 + 16 + n15] = (unsigned short)(u1[r] >> 16);
            }
            bf16x8 Pl = ld_bf16x8(pw + n15 * 40 + quad * 8);

            O0 = __builtin_amdgcn_mfma_f32_16x16x32_bf16(Pl, kv.vl[t][0], O0, 0, 0, 0);
            O0 = __builtin_amdgcn_mfma_f32_16x16x32_bf16(Pl, kv.vh[t][0], O0, 0, 0, 0);
            O0 = __builtin_amdgcn_mfma_f32_16x16x32_bf16(Ph, kv.vl[t][0], O0, 0, 0, 0);
            O0 = __builtin_amdgcn_mfma_f32_16x16x32_bf16(Ph, kv.vh[t][0], O0, 0, 0, 0);
            O1 = __builtin_amdgcn_mfma_f32_16x16x32_bf16(Pl, kv.vl[t][1], O1, 0, 0, 0);
            O1 = __builtin_amdgcn_mfma_f32_16x16x32_bf16(Pl, kv.vh[t][1], O1, 0, 0, 0);
            O1 = __builtin_amdgcn_mfma_f32_16x16x32_bf16(Ph, kv.vl[t][1], O1, 0, 0, 0);
            O1 = __builtin_amdgcn_mfma_f32_16x16x32_bf16(Ph, kv.vh[t][1], O1, 0, 0, 0);
        }
    };

    fetch_chunk(0, 0);
    KVT kv;
    // main loop: last chunk peeled so the prefetch is UNCONDITIONAL here
    // (a conditional fetch would force the waitcnt pass to merge to vmcnt(0)).
    for (int c = 0; c < NC - 1; ++c) {
        const int cur = c & 1;
        __syncthreads();                 // drains chunk-c asyncs: sim resident
        headsum_phase(cur);
        __syncthreads();                 // hsum visible; vmcnt already 0: free
        load_kv(c, kv);                  // K/V/mask first (older in vmcnt order)
        __builtin_amdgcn_sched_barrier(0);
        fetch_chunk(c + 1, cur ^ 1);     // asyncs last: stay in flight
        __builtin_amdgcn_sched_barrier(0);
        chunk_body(cur, kv);             // no barriers; counted vmcnt only
    }
    {
        const int cur = (NC - 1) & 1;
        __syncthreads();
        headsum_phase(cur);
        __syncthreads();
        load_kv(NC - 1, kv);
        chunk_body(cur, kv);
    }

    // epilogue: normalize and write split-bf16 x directly (no split-K combine)
    #pragma unroll
    for (int r = 0; r < 4; ++r) {
        const int q = quad * 4 + r;
        const float inv = 1.0f / l_r[r];
        const size_t base = (size_t)(b * NQ + q0 + q) * C_ + wave * HD;
        unsigned int p0 = split1(O0[r] * inv);
        unsigned int p1 = split1(O1[r] * inv);
        xh[base + n15]      = (unsigned short)p0;
        xl[base + n15]      = (unsigned short)(p0 >> 16);
        xh[base + 16 + n15] = (unsigned short)p1;
        xl[base + 16 + n15] = (unsigned short)(p1 >> 16);
    }
}

extern "C" void kernel_launch(void* const* d_in, const int* in_sizes, int n_in,
                              void* d_out, int out_size, void* d_ws, size_t ws_size,
                              hipStream_t stream) {
    const float* query = (const float*)d_in[0];
    const float* key   = (const float*)d_in[1];
    const float* value = (const float*)d_in[2];
    // d_in[3] qpos, d_in[4] kpos: unused (rope is None)
    const int*   mask  = (const int*)d_in[5];   // bool uploaded as int32
    const float* sim   = (const float*)d_in[6];
    const float* Wq  = (const float*)d_in[7];
    const float* Wk  = (const float*)d_in[8];
    const float* Wv  = (const float*)d_in[9];
    const float* Wp  = (const float*)d_in[10];
    const float* bp  = (const float*)d_in[11];
    float* out = (float*)d_out;

    // workspace: 8 x 2MB bf16 arrays (16 MB) + packed mask bits (0.5 MB)
    const size_t NEL = (size_t)B_ * H_ * NQ * HD;   // 1,048,576
    unsigned short* qbh = (unsigned short*)d_ws;
    unsigned short* qbl = qbh + NEL;
    unsigned short* kbh = qbl + NEL;
    unsigned short* kbl = kbh + NEL;
    unsigned short* vbh = kbl + NEL;
    unsigned short* vbl = vbh + NEL;
    unsigned short* xbh = vbl + NEL;
    unsigned short* xbl = xbh + NEL;
    unsigned short* maskbW = xbl + NEL;             // QT_*NK ushort = 512 KB

    maskpack_kernel<<<dim3(QT_, NK / 256), 256, 0, stream>>>(mask, maskbW);
    proj_kernel<<<dim3(64, 4, 3), 256, 0, stream>>>(query, key, value, Wq, Wk, Wv,
                                                    qbh, qbl, kbh, kbl, vbh, vbl);
    attn_kernel<<<B_ * QT_, 512, 0, stream>>>(qbh, qbl, kbh, kbl, vbh, vbl,
                                              sim, maskbW, xbh, xbl);
    outproj_kernel<<<dim3(64, 4), 256, 0, stream>>>(xbh, xbl, Wp, bp, out);
}